// Round 1
// baseline (2212.581 us; speedup 1.0000x reference)
//
#include <hip/hip_runtime.h>
#include <hip/hip_bf16.h>
#include <math.h>

// Problem constants
#define Bq   2
#define Lq   2048
#define Dq   256
#define NLq  4
#define Nst  16
#define EDq  512
#define Kq   4
#define DTq  16
#define Vq   32000
#define Rq   (Bq*Lq)          // 4096 rows
#define NCq  16               // scan chunks
#define LCq  (Lq/NCq)         // 128 per chunk

// ---------------- embed ----------------
__global__ __launch_bounds__(256) void embed_kernel(const int* __restrict__ x,
                                                    const float* __restrict__ et,
                                                    float* __restrict__ h) {
    int r = blockIdx.x;
    int d = threadIdx.x;
    h[r * Dq + d] = et[x[r] * Dq + d];
}

// ---------------- rmsnorm (block per row, D=256) ----------------
__global__ __launch_bounds__(256) void rmsnorm_kernel(const float* __restrict__ h,
                                                      const float* __restrict__ w,
                                                      float* __restrict__ out) {
    int r = blockIdx.x;
    int d = threadIdx.x;
    float v = h[r * Dq + d];
    float ss = v * v;
#pragma unroll
    for (int o = 32; o > 0; o >>= 1) ss += __shfl_down(ss, o);
    __shared__ float sb[4];
    if ((threadIdx.x & 63) == 0) sb[threadIdx.x >> 6] = ss;
    __syncthreads();
    float tot = sb[0] + sb[1] + sb[2] + sb[3];
    float scale = rsqrtf(tot * (1.0f / Dq) + 1e-5f);
    out[r * Dq + d] = v * scale * w[d];
}

// ---------------- layernorm (block per row, D=256) ----------------
__global__ __launch_bounds__(256) void layernorm_kernel(const float* __restrict__ h,
                                                        const float* __restrict__ w,
                                                        const float* __restrict__ b,
                                                        float* __restrict__ out) {
    int r = blockIdx.x;
    int d = threadIdx.x;
    float v = h[r * Dq + d];
    float s = v, s2 = v * v;
#pragma unroll
    for (int o = 32; o > 0; o >>= 1) { s += __shfl_down(s, o); s2 += __shfl_down(s2, o); }
    __shared__ float sb[8];
    if ((threadIdx.x & 63) == 0) { sb[threadIdx.x >> 6] = s; sb[4 + (threadIdx.x >> 6)] = s2; }
    __syncthreads();
    float S  = sb[0] + sb[1] + sb[2] + sb[3];
    float S2 = sb[4] + sb[5] + sb[6] + sb[7];
    float mu = S * (1.0f / Dq);
    float var = S2 * (1.0f / Dq) - mu * mu;
    out[r * Dq + d] = (v - mu) * rsqrtf(var + 1e-5f) * w[d] + b[d];
}

// ---------------- generic GEMM: C[m,n] (+=) sum_k A[m,k]*W[n,k] (+bias[n]) ----
// 64x64 tile, BK=16, 256 threads, 4x4 per-thread microtile. All dims divisible.
__global__ __launch_bounds__(256) void gemm_bt(const float* __restrict__ A,
                                               const float* __restrict__ W,
                                               const float* __restrict__ bias,
                                               float* __restrict__ C,
                                               int M, int N, int K, int accumulate) {
    __shared__ float As[16][64];
    __shared__ float Ws[16][64];
    int m0 = blockIdx.y * 64, n0 = blockIdx.x * 64;
    int tid = threadIdx.x;
    int tx = tid & 15, ty = tid >> 4;
    int lr = tid >> 2;          // 0..63 (row within tile for staging)
    int lk = (tid & 3) << 2;    // 0,4,8,12 (k offset for staging)
    float acc[4][4] = {};

    for (int kt = 0; kt < K; kt += 16) {
        float4 av = *(const float4*)&A[(size_t)(m0 + lr) * K + kt + lk];
        float4 wv = *(const float4*)&W[(size_t)(n0 + lr) * K + kt + lk];
        __syncthreads();  // previous tile's reads done
        As[lk + 0][lr] = av.x; As[lk + 1][lr] = av.y; As[lk + 2][lr] = av.z; As[lk + 3][lr] = av.w;
        Ws[lk + 0][lr] = wv.x; Ws[lk + 1][lr] = wv.y; Ws[lk + 2][lr] = wv.z; Ws[lk + 3][lr] = wv.w;
        __syncthreads();
#pragma unroll
        for (int k = 0; k < 16; k++) {
            float4 a4 = *(const float4*)&As[k][ty * 4];
            float4 b4 = *(const float4*)&Ws[k][tx * 4];
            float av_[4] = {a4.x, a4.y, a4.z, a4.w};
            float bv_[4] = {b4.x, b4.y, b4.z, b4.w};
#pragma unroll
            for (int i = 0; i < 4; i++)
#pragma unroll
                for (int j = 0; j < 4; j++)
                    acc[i][j] = fmaf(av_[i], bv_[j], acc[i][j]);
        }
    }

#pragma unroll
    for (int i = 0; i < 4; i++) {
        int m = m0 + ty * 4 + i;
        float4 c;
        c.x = acc[i][0]; c.y = acc[i][1]; c.z = acc[i][2]; c.w = acc[i][3];
        if (bias) {
            const float4 bb = *(const float4*)&bias[n0 + tx * 4];
            c.x += bb.x; c.y += bb.y; c.z += bb.z; c.w += bb.w;
        }
        float* dst = &C[(size_t)m * N + n0 + tx * 4];
        if (accumulate) {
            float4 o = *(const float4*)dst;
            c.x += o.x; c.y += o.y; c.z += o.z; c.w += o.w;
        }
        *(float4*)dst = c;
    }
}

// ---------------- causal depthwise conv (K=4) + silu ----------------
// input: x-half of xz (row stride 1024), output xc (row stride 512)
__global__ __launch_bounds__(256) void conv_silu_kernel(const float* __restrict__ xz,
                                                        const float* __restrict__ cw,
                                                        const float* __restrict__ cb,
                                                        float* __restrict__ xc) {
    int e = ((blockIdx.x & 1) << 8) + threadIdx.x;   // 0..511
    int r = blockIdx.x >> 1;                          // 0..4095
    int l = r & (Lq - 1);
    float acc = cb[e];
#pragma unroll
    for (int i = 0; i < 4; i++) {
        int dl = i - 3;
        if (l + dl >= 0) acc = fmaf(xz[(size_t)(r + dl) * 1024 + e], cw[e * 4 + i], acc);
    }
    float s = acc / (1.0f + __expf(-acc));   // silu
    xc[(size_t)r * EDq + e] = s;
}

// ---------------- x_proj: dbc[r, j<48] = sum_k xc[r,k]*Wp[j,k] ----------------
__global__ __launch_bounds__(64) void xproj_kernel(const float* __restrict__ xc,
                                                   const float* __restrict__ Wp,
                                                   float* __restrict__ dbc) {
    __shared__ float row[EDq];
    int r = blockIdx.x;
    for (int k = threadIdx.x; k < EDq; k += 64) row[k] = xc[(size_t)r * EDq + k];
    __syncthreads();
    int j = threadIdx.x;
    if (j < 48) {
        const float* wr = &Wp[j * EDq];
        float acc = 0.f;
        for (int k = 0; k < EDq; k += 4) {
            float4 wv = *(const float4*)&wr[k];
            float4 xv = *(const float4*)&row[k];
            acc = fmaf(wv.x, xv.x, acc);
            acc = fmaf(wv.y, xv.y, acc);
            acc = fmaf(wv.z, xv.z, acc);
            acc = fmaf(wv.w, xv.w, acc);
        }
        dbc[(size_t)r * 48 + j] = acc;
    }
}

// ---------------- dt_proj + softplus ----------------
__global__ __launch_bounds__(256) void dtproj_kernel(const float* __restrict__ dbc,
                                                     const float* __restrict__ dtw,
                                                     const float* __restrict__ dtb,
                                                     float* __restrict__ dlt) {
    int r = blockIdx.x >> 1;
    int e = ((blockIdx.x & 1) << 8) + threadIdx.x;
    const float* dr = &dbc[(size_t)r * 48];
    const float* wr = &dtw[e * 16];
    float acc = dtb[e];
#pragma unroll
    for (int k = 0; k < 16; k++) acc = fmaf(dr[k], wr[k], acc);
    float sp = (acc > 20.f) ? acc : log1pf(__expf(acc));
    dlt[(size_t)r * EDq + e] = sp;
}

// ---------------- scan pass 1: per (b,e,chunk) local scan ----------------
__global__ __launch_bounds__(256) void scan_pass1(const float* __restrict__ dlt,
                                                  const float* __restrict__ xc,
                                                  const float* __restrict__ dbc,
                                                  const float* __restrict__ A_log,
                                                  float* __restrict__ cA,
                                                  float* __restrict__ cB) {
    int gid = blockIdx.x * 256 + threadIdx.x;   // < B*NC*ED = 16384
    int e = gid & (EDq - 1);
    int bc = gid >> 9;                           // b*NC + c
    int rbase = bc << 7;                         // = b*L + c*LC

    float Aa[16];
#pragma unroll
    for (int n = 0; n < 16; n++) Aa[n] = -__expf(A_log[e * 16 + n]);
    float pA[16], hB[16];
#pragma unroll
    for (int n = 0; n < 16; n++) { pA[n] = 1.f; hB[n] = 0.f; }

    for (int t = 0; t < LCq; t++) {
        int r = rbase + t;
        float d = dlt[(size_t)r * EDq + e];
        float xv = xc[(size_t)r * EDq + e];
        float dx = d * xv;
        const float4* Bp = (const float4*)&dbc[(size_t)r * 48 + 16];
        float4 B0 = Bp[0], B1 = Bp[1], B2 = Bp[2], B3 = Bp[3];
        float Bm[16] = {B0.x, B0.y, B0.z, B0.w, B1.x, B1.y, B1.z, B1.w,
                        B2.x, B2.y, B2.z, B2.w, B3.x, B3.y, B3.z, B3.w};
#pragma unroll
        for (int n = 0; n < 16; n++) {
            float dA = __expf(d * Aa[n]);
            hB[n] = fmaf(dA, hB[n], dx * Bm[n]);
            pA[n] *= dA;
        }
    }
    size_t ob = (size_t)gid * 16;
#pragma unroll
    for (int n = 0; n < 16; n++) { cA[ob + n] = pA[n]; cB[ob + n] = hB[n]; }
}

// ---------------- scan chunk combine (sequential over 16 chunks) ----------------
__global__ __launch_bounds__(256) void scan_combine(const float* __restrict__ cA,
                                                    const float* __restrict__ cB,
                                                    float* __restrict__ cP) {
    int idx = blockIdx.x * 256 + threadIdx.x;   // < B*ED*N = 16384
    int en = idx & 8191;                         // e*16+n
    int b = idx >> 13;
    float hc = 0.f;
    for (int c = 0; c < NCq; c++) {
        size_t base = ((size_t)(b * NCq + c) << 13) + en;
        cP[base] = hc;
        hc = fmaf(cA[base], hc, cB[base]);
    }
}

// ---------------- scan pass 2: recompute with prefix, fuse y = (hs.C + D*xc)*silu(z) ----
__global__ __launch_bounds__(256) void scan_pass2(const float* __restrict__ dlt,
                                                  const float* __restrict__ xc,
                                                  const float* __restrict__ dbc,
                                                  const float* __restrict__ A_log,
                                                  const float* __restrict__ cP,
                                                  const float* __restrict__ Dp,
                                                  const float* __restrict__ xz,
                                                  float* __restrict__ y) {
    int gid = blockIdx.x * 256 + threadIdx.x;
    int e = gid & (EDq - 1);
    int bc = gid >> 9;
    int rbase = bc << 7;

    float Aa[16];
#pragma unroll
    for (int n = 0; n < 16; n++) Aa[n] = -__expf(A_log[e * 16 + n]);
    float hh[16];
    size_t pb = (size_t)gid * 16;
#pragma unroll
    for (int n = 0; n < 16; n++) hh[n] = cP[pb + n];
    float Dv = Dp[e];

    for (int t = 0; t < LCq; t++) {
        int r = rbase + t;
        float d = dlt[(size_t)r * EDq + e];
        float xv = xc[(size_t)r * EDq + e];
        float dx = d * xv;
        const float4* Bp = (const float4*)&dbc[(size_t)r * 48 + 16];
        float4 B0 = Bp[0], B1 = Bp[1], B2 = Bp[2], B3 = Bp[3];
        float Bm[16] = {B0.x, B0.y, B0.z, B0.w, B1.x, B1.y, B1.z, B1.w,
                        B2.x, B2.y, B2.z, B2.w, B3.x, B3.y, B3.z, B3.w};
        const float4* Cp = (const float4*)&dbc[(size_t)r * 48 + 32];
        float4 C0 = Cp[0], C1 = Cp[1], C2 = Cp[2], C3 = Cp[3];
        float Cm[16] = {C0.x, C0.y, C0.z, C0.w, C1.x, C1.y, C1.z, C1.w,
                        C2.x, C2.y, C2.z, C2.w, C3.x, C3.y, C3.z, C3.w};
        float cacc = 0.f;
#pragma unroll
        for (int n = 0; n < 16; n++) {
            float dA = __expf(d * Aa[n]);
            hh[n] = fmaf(dA, hh[n], dx * Bm[n]);
            cacc = fmaf(hh[n], Cm[n], cacc);
        }
        float yv = fmaf(Dv, xv, cacc);
        float zv = xz[(size_t)r * 1024 + EDq + e];
        float sz = zv / (1.0f + __expf(-zv));
        y[(size_t)r * EDq + e] = yv * sz;
    }
}

// ---------------- launch ----------------
extern "C" void kernel_launch(void* const* d_in, const int* in_sizes, int n_in,
                              void* d_out, int out_size, void* d_ws, size_t ws_size,
                              hipStream_t stream) {
    const int*   x         = (const int*)d_in[0];
    const float* embed_t   = (const float*)d_in[1];
    const float* rms_w     = (const float*)d_in[2];
    const float* in_proj_w = (const float*)d_in[3];
    const float* conv_w    = (const float*)d_in[4];
    const float* conv_b    = (const float*)d_in[5];
    const float* x_proj_w  = (const float*)d_in[6];
    const float* dt_proj_w = (const float*)d_in[7];
    const float* dt_proj_b = (const float*)d_in[8];
    const float* A_log     = (const float*)d_in[9];
    const float* D_p       = (const float*)d_in[10];
    const float* out_proj_w= (const float*)d_in[11];
    const float* norm_w    = (const float*)d_in[12];
    const float* norm_b    = (const float*)d_in[13];
    const float* head_w    = (const float*)d_in[14];
    const float* head_b    = (const float*)d_in[15];
    float* out = (float*)d_out;

    float* ws = (float*)d_ws;
    float* h    = ws;                    // R*D      = 1,048,576
    float* xin  = h    + (size_t)Rq * Dq;       // R*D
    float* xz   = xin  + (size_t)Rq * Dq;       // R*1024  = 4,194,304
    float* xc   = xz   + (size_t)Rq * 1024;     // R*ED    = 2,097,152
    float* dbc  = xc   + (size_t)Rq * EDq;      // R*48    = 196,608
    float* dlt  = dbc  + (size_t)Rq * 48;       // R*ED
    float* yb   = dlt  + (size_t)Rq * EDq;      // R*ED
    float* cA   = yb   + (size_t)Rq * EDq;      // B*NC*ED*N = 262,144
    float* cB   = cA   + 262144;
    float* cP   = cB   + 262144;
    float* hn   = cP   + 262144;                // R*D

    embed_kernel<<<Rq, 256, 0, stream>>>(x, embed_t, h);

    for (int i = 0; i < NLq; i++) {
        rmsnorm_kernel<<<Rq, 256, 0, stream>>>(h, rms_w + i * Dq, xin);
        gemm_bt<<<dim3(1024 / 64, Rq / 64), 256, 0, stream>>>(
            xin, in_proj_w + (size_t)i * 1024 * Dq, nullptr, xz, Rq, 1024, Dq, 0);
        conv_silu_kernel<<<Rq * 2, 256, 0, stream>>>(
            xz, conv_w + i * EDq * Kq, conv_b + i * EDq, xc);
        xproj_kernel<<<Rq, 64, 0, stream>>>(xc, x_proj_w + (size_t)i * 48 * EDq, dbc);
        dtproj_kernel<<<Rq * 2, 256, 0, stream>>>(
            dbc, dt_proj_w + i * EDq * DTq, dt_proj_b + i * EDq, dlt);
        scan_pass1<<<64, 256, 0, stream>>>(dlt, xc, dbc, A_log + i * EDq * Nst, cA, cB);
        scan_combine<<<64, 256, 0, stream>>>(cA, cB, cP);
        scan_pass2<<<64, 256, 0, stream>>>(dlt, xc, dbc, A_log + i * EDq * Nst, cP,
                                           D_p + i * EDq, xz, yb);
        gemm_bt<<<dim3(Dq / 64, Rq / 64), 256, 0, stream>>>(
            yb, out_proj_w + (size_t)i * Dq * EDq, nullptr, h, Rq, Dq, EDq, 1);
    }

    layernorm_kernel<<<Rq, 256, 0, stream>>>(h, norm_w, norm_b, hn);
    gemm_bt<<<dim3(Vq / 64, Rq / 64), 256, 0, stream>>>(
        hn, head_w, head_b, out, Rq, Vq, Dq, 0);
}

// Round 2
// 889.994 us; speedup vs baseline: 2.4861x; 2.4861x over previous
//
#include <hip/hip_runtime.h>
#include <hip/hip_bf16.h>
#include <math.h>

// Problem constants
#define Bq   2
#define Lq   2048
#define Dq   256
#define NLq  4
#define Nst  16
#define EDq  512
#define Kq   4
#define DTq  16
#define Vq   32000
#define Rq   (Bq*Lq)          // 4096 rows
#define NCq  64               // scan chunks
#define LCq  (Lq/NCq)         // 32 per chunk

typedef __attribute__((ext_vector_type(8))) __bf16 bf16x8v;
typedef __attribute__((ext_vector_type(4))) float f32x4v;
typedef __attribute__((address_space(1))) const void GV;
typedef __attribute__((address_space(3))) void LV;

__device__ __forceinline__ unsigned short to_bf16(float f) {
    unsigned int u = __float_as_uint(f);
    unsigned int r = (u + 0x7FFFu + ((u >> 16) & 1u)) >> 16;
    return (unsigned short)r;
}

// ---------------- f32 -> bf16 weight conversion (4 elems/thread) ----------------
__global__ __launch_bounds__(256) void convert_bf16(const float* __restrict__ in,
                                                    unsigned short* __restrict__ out, int n) {
    int i = (blockIdx.x * 256 + threadIdx.x) * 4;
    if (i + 3 < n) {
        float4 v = *(const float4*)&in[i];
        ushort4 o;
        o.x = to_bf16(v.x); o.y = to_bf16(v.y); o.z = to_bf16(v.z); o.w = to_bf16(v.w);
        *(ushort4*)&out[i] = o;
    }
}

// ---------------- embed ----------------
__global__ __launch_bounds__(256) void embed_kernel(const int* __restrict__ x,
                                                    const float* __restrict__ et,
                                                    float* __restrict__ h) {
    int r = blockIdx.x;
    int d = threadIdx.x;
    h[r * Dq + d] = et[x[r] * Dq + d];
}

// ---------------- rmsnorm (block per row, D=256), bf16 out ----------------
__global__ __launch_bounds__(256) void rmsnorm_kernel(const float* __restrict__ h,
                                                      const float* __restrict__ w,
                                                      unsigned short* __restrict__ out) {
    int r = blockIdx.x;
    int d = threadIdx.x;
    float v = h[r * Dq + d];
    float ss = v * v;
#pragma unroll
    for (int o = 32; o > 0; o >>= 1) ss += __shfl_down(ss, o);
    __shared__ float sb[4];
    if ((threadIdx.x & 63) == 0) sb[threadIdx.x >> 6] = ss;
    __syncthreads();
    float tot = sb[0] + sb[1] + sb[2] + sb[3];
    float scale = rsqrtf(tot * (1.0f / Dq) + 1e-5f);
    out[r * Dq + d] = to_bf16(v * scale * w[d]);
}

// ---------------- layernorm (block per row, D=256), bf16 out ----------------
__global__ __launch_bounds__(256) void layernorm_kernel(const float* __restrict__ h,
                                                        const float* __restrict__ w,
                                                        const float* __restrict__ b,
                                                        unsigned short* __restrict__ out) {
    int r = blockIdx.x;
    int d = threadIdx.x;
    float v = h[r * Dq + d];
    float s = v, s2 = v * v;
#pragma unroll
    for (int o = 32; o > 0; o >>= 1) { s += __shfl_down(s, o); s2 += __shfl_down(s2, o); }
    __shared__ float sb[8];
    if ((threadIdx.x & 63) == 0) { sb[threadIdx.x >> 6] = s; sb[4 + (threadIdx.x >> 6)] = s2; }
    __syncthreads();
    float S  = sb[0] + sb[1] + sb[2] + sb[3];
    float S2 = sb[4] + sb[5] + sb[6] + sb[7];
    float mu = S * (1.0f / Dq);
    float var = S2 * (1.0f / Dq) - mu * mu;
    out[r * Dq + d] = to_bf16((v - mu) * rsqrtf(var + 1e-5f) * w[d] + b[d]);
}

// ---------------- bf16 MFMA GEMM: C[m,n] (+=) sum_k A[m,k]*W[n,k] (+bias[n]) ----
// m97 structure: 128x128 tile, BK=32, 4 waves, 4x4 16x16 fragments per wave,
// global_load_lds width=16, linear LDS. M,N div by 128; K div by 32.
__global__ __launch_bounds__(256) void gemm_mfma_bt(const unsigned short* __restrict__ A,
                                                    const unsigned short* __restrict__ W,
                                                    const float* __restrict__ bias,
                                                    float* __restrict__ C,
                                                    int M, int N, int K, int accumulate) {
    __shared__ unsigned short As[128 * 32];
    __shared__ unsigned short Bs[128 * 32];
    const int m0 = blockIdx.y * 128, n0 = blockIdx.x * 128;
    const int tid = threadIdx.x;
    const int wid = tid >> 6, lane = tid & 63;
    const int wm = wid >> 1, wn = wid & 1;

    f32x4v acc[4][4];
#pragma unroll
    for (int i = 0; i < 4; i++)
#pragma unroll
        for (int j = 0; j < 4; j++) acc[i][j] = (f32x4v){0.f, 0.f, 0.f, 0.f};

    // staging: wave wid stages tile rows [wid*32, wid*32+32) for both A and B.
    // lane l of load q covers row wid*32 + q*16 + (l>>2), k-offset (l&3)*8.
    // LDS offset == base + lane*8 elements (16B/lane, contiguous) as required.
    const int srow = wid * 32 + (lane >> 2);
    const int skoff = (lane & 3) * 8;
    const unsigned short* gA  = A + (size_t)(m0 + srow) * K + skoff;
    const unsigned short* gA2 = gA + (size_t)16 * K;
    const unsigned short* gW  = W + (size_t)(n0 + srow) * K + skoff;
    const unsigned short* gW2 = gW + (size_t)16 * K;
    unsigned short* lA = As + wid * 1024 + lane * 8;
    unsigned short* lB = Bs + wid * 1024 + lane * 8;

    const int l15 = lane & 15, lk = (lane >> 4) * 8;

    for (int kt = 0; kt < K; kt += 32) {
        __syncthreads();  // previous iteration's ds_reads complete
        __builtin_amdgcn_global_load_lds((GV*)(gA + kt),  (LV*)lA,         16, 0, 0);
        __builtin_amdgcn_global_load_lds((GV*)(gA2 + kt), (LV*)(lA + 512), 16, 0, 0);
        __builtin_amdgcn_global_load_lds((GV*)(gW + kt),  (LV*)lB,         16, 0, 0);
        __builtin_amdgcn_global_load_lds((GV*)(gW2 + kt), (LV*)(lB + 512), 16, 0, 0);
        __syncthreads();  // drains vmcnt(0): staged data visible

        bf16x8v a[4], b[4];
#pragma unroll
        for (int i = 0; i < 4; i++)
            a[i] = *(const bf16x8v*)&As[(wm * 64 + i * 16 + l15) * 32 + lk];
#pragma unroll
        for (int j = 0; j < 4; j++)
            b[j] = *(const bf16x8v*)&Bs[(wn * 64 + j * 16 + l15) * 32 + lk];
#pragma unroll
        for (int i = 0; i < 4; i++)
#pragma unroll
            for (int j = 0; j < 4; j++)
                acc[i][j] = __builtin_amdgcn_mfma_f32_16x16x32_bf16(a[i], b[j], acc[i][j], 0, 0, 0);
    }

    // epilogue: C/D layout col=lane&15, row=(lane>>4)*4+reg  [m89-verified]
    const int rbase = m0 + wm * 64 + (lane >> 4) * 4;
    const int cbase = n0 + wn * 64 + l15;
#pragma unroll
    for (int i = 0; i < 4; i++) {
#pragma unroll
        for (int j = 0; j < 4; j++) {
            int col = cbase + j * 16;
            float bv = bias ? bias[col] : 0.f;
#pragma unroll
            for (int r = 0; r < 4; r++) {
                int row = rbase + i * 16 + r;
                float v = acc[i][j][r] + bv;
                float* dst = &C[(size_t)row * N + col];
                if (accumulate) v += *dst;
                *dst = v;
            }
        }
    }
}

// ---------------- causal depthwise conv (K=4) + silu ----------------
__global__ __launch_bounds__(256) void conv_silu_kernel(const float* __restrict__ xz,
                                                        const float* __restrict__ cw,
                                                        const float* __restrict__ cb,
                                                        float* __restrict__ xc) {
    int e = ((blockIdx.x & 1) << 8) + threadIdx.x;   // 0..511
    int r = blockIdx.x >> 1;                          // 0..4095
    int l = r & (Lq - 1);
    float acc = cb[e];
#pragma unroll
    for (int i = 0; i < 4; i++) {
        int dl = i - 3;
        if (l + dl >= 0) acc = fmaf(xz[(size_t)(r + dl) * 1024 + e], cw[e * 4 + i], acc);
    }
    float s = acc / (1.0f + __expf(-acc));   // silu
    xc[(size_t)r * EDq + e] = s;
}

// ---------------- x_proj: dbc[r, j<48] = sum_k xc[r,k]*Wp[j,k] ----------------
__global__ __launch_bounds__(64) void xproj_kernel(const float* __restrict__ xc,
                                                   const float* __restrict__ Wp,
                                                   float* __restrict__ dbc) {
    __shared__ float row[EDq];
    int r = blockIdx.x;
    for (int k = threadIdx.x; k < EDq; k += 64) row[k] = xc[(size_t)r * EDq + k];
    __syncthreads();
    int j = threadIdx.x;
    if (j < 48) {
        const float* wr = &Wp[j * EDq];
        float acc = 0.f;
        for (int k = 0; k < EDq; k += 4) {
            float4 wv = *(const float4*)&wr[k];
            float4 xv = *(const float4*)&row[k];
            acc = fmaf(wv.x, xv.x, acc);
            acc = fmaf(wv.y, xv.y, acc);
            acc = fmaf(wv.z, xv.z, acc);
            acc = fmaf(wv.w, xv.w, acc);
        }
        dbc[(size_t)r * 48 + j] = acc;
    }
}

// ---------------- dt_proj + softplus ----------------
__global__ __launch_bounds__(256) void dtproj_kernel(const float* __restrict__ dbc,
                                                     const float* __restrict__ dtw,
                                                     const float* __restrict__ dtb,
                                                     float* __restrict__ dlt) {
    int r = blockIdx.x >> 1;
    int e = ((blockIdx.x & 1) << 8) + threadIdx.x;
    const float* dr = &dbc[(size_t)r * 48];
    const float* wr = &dtw[e * 16];
    float acc = dtb[e];
#pragma unroll
    for (int k = 0; k < 16; k++) acc = fmaf(dr[k], wr[k], acc);
    float sp = (acc > 20.f) ? acc : log1pf(__expf(acc));
    dlt[(size_t)r * EDq + e] = sp;
}

// ---------------- scan pass 1: per (b,e,chunk) local scan ----------------
__global__ __launch_bounds__(256) void scan_pass1(const float* __restrict__ dlt,
                                                  const float* __restrict__ xc,
                                                  const float* __restrict__ dbc,
                                                  const float* __restrict__ A_log,
                                                  float* __restrict__ cA,
                                                  float* __restrict__ cB) {
    int gid = blockIdx.x * 256 + threadIdx.x;   // < B*NC*ED = 65536
    int e = gid & (EDq - 1);
    int bc = gid >> 9;                           // b*NC + c
    int rbase = bc * LCq;

    float Aa[16];
#pragma unroll
    for (int n = 0; n < 16; n++) Aa[n] = -__expf(A_log[e * 16 + n]);
    float pA[16], hB[16];
#pragma unroll
    for (int n = 0; n < 16; n++) { pA[n] = 1.f; hB[n] = 0.f; }

    for (int t = 0; t < LCq; t++) {
        int r = rbase + t;
        float d = dlt[(size_t)r * EDq + e];
        float xv = xc[(size_t)r * EDq + e];
        float dx = d * xv;
        const float4* Bp = (const float4*)&dbc[(size_t)r * 48 + 16];
        float4 B0 = Bp[0], B1 = Bp[1], B2 = Bp[2], B3 = Bp[3];
        float Bm[16] = {B0.x, B0.y, B0.z, B0.w, B1.x, B1.y, B1.z, B1.w,
                        B2.x, B2.y, B2.z, B2.w, B3.x, B3.y, B3.z, B3.w};
#pragma unroll
        for (int n = 0; n < 16; n++) {
            float dA = __expf(d * Aa[n]);
            hB[n] = fmaf(dA, hB[n], dx * Bm[n]);
            pA[n] *= dA;
        }
    }
    size_t ob = (size_t)gid * 16;
#pragma unroll
    for (int n = 0; n < 16; n++) { cA[ob + n] = pA[n]; cB[ob + n] = hB[n]; }
}

// ---------------- scan chunk combine (sequential over NC chunks) ----------------
__global__ __launch_bounds__(256) void scan_combine(const float* __restrict__ cA,
                                                    const float* __restrict__ cB,
                                                    float* __restrict__ cP) {
    int idx = blockIdx.x * 256 + threadIdx.x;   // < B*ED*N = 16384
    int en = idx & 8191;                         // e*16+n
    int b = idx >> 13;
    float hc = 0.f;
    for (int c = 0; c < NCq; c++) {
        size_t base = ((size_t)(b * NCq + c) << 13) + en;
        cP[base] = hc;
        hc = fmaf(cA[base], hc, cB[base]);
    }
}

// ---------------- scan pass 2: recompute with prefix, fuse y = (hs.C + D*xc)*silu(z) ----
// writes y as bf16 (feeds out_proj MFMA GEMM)
__global__ __launch_bounds__(256) void scan_pass2(const float* __restrict__ dlt,
                                                  const float* __restrict__ xc,
                                                  const float* __restrict__ dbc,
                                                  const float* __restrict__ A_log,
                                                  const float* __restrict__ cP,
                                                  const float* __restrict__ Dp,
                                                  const float* __restrict__ xz,
                                                  unsigned short* __restrict__ y) {
    int gid = blockIdx.x * 256 + threadIdx.x;
    int e = gid & (EDq - 1);
    int bc = gid >> 9;
    int rbase = bc * LCq;

    float Aa[16];
#pragma unroll
    for (int n = 0; n < 16; n++) Aa[n] = -__expf(A_log[e * 16 + n]);
    float hh[16];
    size_t pb = (size_t)gid * 16;
#pragma unroll
    for (int n = 0; n < 16; n++) hh[n] = cP[pb + n];
    float Dv = Dp[e];

    for (int t = 0; t < LCq; t++) {
        int r = rbase + t;
        float d = dlt[(size_t)r * EDq + e];
        float xv = xc[(size_t)r * EDq + e];
        float dx = d * xv;
        const float4* Bp = (const float4*)&dbc[(size_t)r * 48 + 16];
        float4 B0 = Bp[0], B1 = Bp[1], B2 = Bp[2], B3 = Bp[3];
        float Bm[16] = {B0.x, B0.y, B0.z, B0.w, B1.x, B1.y, B1.z, B1.w,
                        B2.x, B2.y, B2.z, B2.w, B3.x, B3.y, B3.z, B3.w};
        const float4* Cp = (const float4*)&dbc[(size_t)r * 48 + 32];
        float4 C0 = Cp[0], C1 = Cp[1], C2 = Cp[2], C3 = Cp[3];
        float Cm[16] = {C0.x, C0.y, C0.z, C0.w, C1.x, C1.y, C1.z, C1.w,
                        C2.x, C2.y, C2.z, C2.w, C3.x, C3.y, C3.z, C3.w};
        float cacc = 0.f;
#pragma unroll
        for (int n = 0; n < 16; n++) {
            float dA = __expf(d * Aa[n]);
            hh[n] = fmaf(dA, hh[n], dx * Bm[n]);
            cacc = fmaf(hh[n], Cm[n], cacc);
        }
        float yv = fmaf(Dv, xv, cacc);
        float zv = xz[(size_t)r * 1024 + EDq + e];
        float sz = zv / (1.0f + __expf(-zv));
        y[(size_t)r * EDq + e] = to_bf16(yv * sz);
    }
}

// ---------------- launch ----------------
extern "C" void kernel_launch(void* const* d_in, const int* in_sizes, int n_in,
                              void* d_out, int out_size, void* d_ws, size_t ws_size,
                              hipStream_t stream) {
    const int*   x         = (const int*)d_in[0];
    const float* embed_t   = (const float*)d_in[1];
    const float* rms_w     = (const float*)d_in[2];
    const float* in_proj_w = (const float*)d_in[3];
    const float* conv_w    = (const float*)d_in[4];
    const float* conv_b    = (const float*)d_in[5];
    const float* x_proj_w  = (const float*)d_in[6];
    const float* dt_proj_w = (const float*)d_in[7];
    const float* dt_proj_b = (const float*)d_in[8];
    const float* A_log     = (const float*)d_in[9];
    const float* D_p       = (const float*)d_in[10];
    const float* out_proj_w= (const float*)d_in[11];
    const float* norm_w    = (const float*)d_in[12];
    const float* norm_b    = (const float*)d_in[13];
    const float* head_w    = (const float*)d_in[14];
    const float* head_b    = (const float*)d_in[15];
    float* out = (float*)d_out;

    float* ws = (float*)d_ws;
    float* h    = ws;                           // R*D
    float* xz   = h    + (size_t)Rq * Dq;       // R*1024
    float* xc   = xz   + (size_t)Rq * 1024;     // R*ED
    float* dbc  = xc   + (size_t)Rq * EDq;      // R*48
    float* dlt  = dbc  + (size_t)Rq * 48;       // R*ED
    float* cA   = dlt  + (size_t)Rq * EDq;      // B*NC*ED*N = 1,048,576
    float* cB   = cA   + (size_t)Bq * NCq * EDq * Nst;
    float* cP   = cB   + (size_t)Bq * NCq * EDq * Nst;
    float* fend = cP   + (size_t)Bq * NCq * EDq * Nst;

    unsigned short* xin16 = (unsigned short*)fend;          // R*D bf16
    unsigned short* yb16  = xin16 + (size_t)Rq * Dq;        // R*ED bf16
    unsigned short* hn16  = yb16  + (size_t)Rq * EDq;       // R*D bf16
    unsigned short* w16i  = hn16  + (size_t)Rq * Dq;        // 4*1024*256
    unsigned short* w16o  = w16i  + (size_t)NLq * 1024 * Dq;  // 4*256*512
    unsigned short* w16h  = w16o  + (size_t)NLq * Dq * EDq;   // 32000*256

    // weight conversions (per-call, deterministic; ~50 MB traffic)
    convert_bf16<<<(NLq * 1024 * Dq) / 1024, 256, 0, stream>>>(in_proj_w, w16i, NLq * 1024 * Dq);
    convert_bf16<<<(NLq * Dq * EDq) / 1024, 256, 0, stream>>>(out_proj_w, w16o, NLq * Dq * EDq);
    convert_bf16<<<(Vq * Dq) / 1024, 256, 0, stream>>>(head_w, w16h, Vq * Dq);

    embed_kernel<<<Rq, 256, 0, stream>>>(x, embed_t, h);

    for (int i = 0; i < NLq; i++) {
        rmsnorm_kernel<<<Rq, 256, 0, stream>>>(h, rms_w + i * Dq, xin16);
        gemm_mfma_bt<<<dim3(1024 / 128, Rq / 128), 256, 0, stream>>>(
            xin16, w16i + (size_t)i * 1024 * Dq, nullptr, xz, Rq, 1024, Dq, 0);
        conv_silu_kernel<<<Rq * 2, 256, 0, stream>>>(
            xz, conv_w + i * EDq * Kq, conv_b + i * EDq, xc);
        xproj_kernel<<<Rq, 64, 0, stream>>>(xc, x_proj_w + (size_t)i * 48 * EDq, dbc);
        dtproj_kernel<<<Rq * 2, 256, 0, stream>>>(
            dbc, dt_proj_w + i * EDq * DTq, dt_proj_b + i * EDq, dlt);
        scan_pass1<<<(Bq * NCq * EDq) / 256, 256, 0, stream>>>(
            dlt, xc, dbc, A_log + i * EDq * Nst, cA, cB);
        scan_combine<<<64, 256, 0, stream>>>(cA, cB, cP);
        scan_pass2<<<(Bq * NCq * EDq) / 256, 256, 0, stream>>>(
            dlt, xc, dbc, A_log + i * EDq * Nst, cP, D_p + i * EDq, xz, yb16);
        gemm_mfma_bt<<<dim3(Dq / 128, Rq / 128), 256, 0, stream>>>(
            yb16, w16o + (size_t)i * Dq * EDq, nullptr, h, Rq, Dq, EDq, 1);
    }

    layernorm_kernel<<<Rq, 256, 0, stream>>>(h, norm_w, norm_b, hn16);
    gemm_mfma_bt<<<dim3(Vq / 128, Rq / 128), 256, 0, stream>>>(
        hn16, w16h, head_b, out, Rq, Vq, Dq, 0);
}

// Round 3
// 813.985 us; speedup vs baseline: 2.7182x; 1.0934x over previous
//
#include <hip/hip_runtime.h>
#include <hip/hip_bf16.h>
#include <math.h>

// Problem constants
#define Bq   2
#define Lq   2048
#define Dq   256
#define NLq  4
#define Nst  16
#define EDq  512
#define Kq   4
#define DTq  16
#define Vq   32000
#define Rq   (Bq*Lq)          // 4096 rows
#define NCq  64               // scan chunks
#define LCq  (Lq/NCq)         // 32 per chunk

typedef __attribute__((ext_vector_type(8))) __bf16 bf16x8v;
typedef __attribute__((ext_vector_type(4))) float f32x4v;
typedef __attribute__((address_space(1))) const void GV;
typedef __attribute__((address_space(3))) void LV;

__device__ __forceinline__ unsigned short to_bf16(float f) {
    unsigned int u = __float_as_uint(f);
    unsigned int r = (u + 0x7FFFu + ((u >> 16) & 1u)) >> 16;
    return (unsigned short)r;
}

// ---------------- f32 -> bf16 weight conversion (4 elems/thread) ----------------
__global__ __launch_bounds__(256) void convert_bf16(const float* __restrict__ in,
                                                    unsigned short* __restrict__ out, int n) {
    int i = (blockIdx.x * 256 + threadIdx.x) * 4;
    if (i + 3 < n) {
        float4 v = *(const float4*)&in[i];
        ushort4 o;
        o.x = to_bf16(v.x); o.y = to_bf16(v.y); o.z = to_bf16(v.z); o.w = to_bf16(v.w);
        *(ushort4*)&out[i] = o;
    }
}

// ---------------- embed ----------------
__global__ __launch_bounds__(256) void embed_kernel(const int* __restrict__ x,
                                                    const float* __restrict__ et,
                                                    float* __restrict__ h) {
    int r = blockIdx.x;
    int d = threadIdx.x;
    h[r * Dq + d] = et[x[r] * Dq + d];
}

// ---------------- rmsnorm (block per row, D=256), bf16 out ----------------
__global__ __launch_bounds__(256) void rmsnorm_kernel(const float* __restrict__ h,
                                                      const float* __restrict__ w,
                                                      unsigned short* __restrict__ out) {
    int r = blockIdx.x;
    int d = threadIdx.x;
    float v = h[r * Dq + d];
    float ss = v * v;
#pragma unroll
    for (int o = 32; o > 0; o >>= 1) ss += __shfl_down(ss, o);
    __shared__ float sb[4];
    if ((threadIdx.x & 63) == 0) sb[threadIdx.x >> 6] = ss;
    __syncthreads();
    float tot = sb[0] + sb[1] + sb[2] + sb[3];
    float scale = rsqrtf(tot * (1.0f / Dq) + 1e-5f);
    out[r * Dq + d] = to_bf16(v * scale * w[d]);
}

// ---------------- layernorm (block per row, D=256), bf16 out ----------------
__global__ __launch_bounds__(256) void layernorm_kernel(const float* __restrict__ h,
                                                        const float* __restrict__ w,
                                                        const float* __restrict__ b,
                                                        unsigned short* __restrict__ out) {
    int r = blockIdx.x;
    int d = threadIdx.x;
    float v = h[r * Dq + d];
    float s = v, s2 = v * v;
#pragma unroll
    for (int o = 32; o > 0; o >>= 1) { s += __shfl_down(s, o); s2 += __shfl_down(s2, o); }
    __shared__ float sb[8];
    if ((threadIdx.x & 63) == 0) { sb[threadIdx.x >> 6] = s; sb[4 + (threadIdx.x >> 6)] = s2; }
    __syncthreads();
    float S  = sb[0] + sb[1] + sb[2] + sb[3];
    float S2 = sb[4] + sb[5] + sb[6] + sb[7];
    float mu = S * (1.0f / Dq);
    float var = S2 * (1.0f / Dq) - mu * mu;
    out[r * Dq + d] = to_bf16((v - mu) * rsqrtf(var + 1e-5f) * w[d] + b[d]);
}

// ---------------- bf16 MFMA GEMM: C[m,n] (+=) sum_k A[m,k]*W[n,k] (+bias[n]) ----
// m97 structure: 128xBN tile, BK=32, 4 waves, global_load_lds width=16, linear LDS,
// bijective XCD swizzle (all grids here are %8==0). M div 128, N div BN, K div 32.
template<int BN>
__global__ __launch_bounds__(256) void gemm_mfma(const unsigned short* __restrict__ A,
                                                 const unsigned short* __restrict__ W,
                                                 const float* __restrict__ bias,
                                                 float* __restrict__ C,
                                                 int M, int N, int K, int accumulate) {
    __shared__ unsigned short As[128 * 32];
    __shared__ unsigned short Bs[BN * 32];

    // XCD-aware bijective swizzle of the flattened block id
    const int gx = gridDim.x;
    const int nwg = gx * gridDim.y;
    int flat = blockIdx.y * gx + blockIdx.x;
    if ((nwg & 7) == 0) {
        int cpx = nwg >> 3;
        flat = (flat & 7) * cpx + (flat >> 3);
    }
    const int m0 = (flat / gx) * 128, n0 = (flat % gx) * BN;

    const int tid = threadIdx.x;
    const int wid = tid >> 6, lane = tid & 63;
    constexpr int MR = (BN == 128) ? 4 : 2;          // M fragments per wave
    const int wrow = (BN == 128) ? (wid >> 1) * 64 : wid * 32;
    const int wcol = (BN == 128) ? (wid & 1) * 64 : 0;

    f32x4v acc[MR][4];
#pragma unroll
    for (int i = 0; i < MR; i++)
#pragma unroll
        for (int j = 0; j < 4; j++) acc[i][j] = (f32x4v){0.f, 0.f, 0.f, 0.f};

    const int srow = lane >> 2;          // 0..15
    const int skoff = (lane & 3) * 8;    // 0,8,16,24
    const unsigned short* gA = A + (size_t)(m0 + wid * 32 + srow) * K + skoff;
    unsigned short* lA = As + wid * 1024 + lane * 8;
    const unsigned short* gW;
    unsigned short* lB;
    if constexpr (BN == 128) { gW = W + (size_t)(n0 + wid * 32 + srow) * K + skoff; lB = Bs + wid * 1024 + lane * 8; }
    else                     { gW = W + (size_t)(n0 + wid * 16 + srow) * K + skoff; lB = Bs + wid * 512  + lane * 8; }

    const int l15 = lane & 15, lk = (lane >> 4) * 8;

    for (int kt = 0; kt < K; kt += 32) {
        __syncthreads();  // previous iteration's ds_reads complete
        __builtin_amdgcn_global_load_lds((GV*)(gA + kt),                   (LV*)lA,         16, 0, 0);
        __builtin_amdgcn_global_load_lds((GV*)(gA + kt + (size_t)16 * K),  (LV*)(lA + 512), 16, 0, 0);
        if constexpr (BN == 128) {
            __builtin_amdgcn_global_load_lds((GV*)(gW + kt),                  (LV*)lB,         16, 0, 0);
            __builtin_amdgcn_global_load_lds((GV*)(gW + kt + (size_t)16 * K), (LV*)(lB + 512), 16, 0, 0);
        } else {
            __builtin_amdgcn_global_load_lds((GV*)(gW + kt),                  (LV*)lB,         16, 0, 0);
        }
        __syncthreads();  // drains vmcnt(0): staged data visible

        bf16x8v a[MR], b[4];
#pragma unroll
        for (int i = 0; i < MR; i++)
            a[i] = *(const bf16x8v*)&As[(wrow + i * 16 + l15) * 32 + lk];
#pragma unroll
        for (int j = 0; j < 4; j++)
            b[j] = *(const bf16x8v*)&Bs[(wcol + j * 16 + l15) * 32 + lk];
#pragma unroll
        for (int i = 0; i < MR; i++)
#pragma unroll
            for (int j = 0; j < 4; j++)
                acc[i][j] = __builtin_amdgcn_mfma_f32_16x16x32_bf16(a[i], b[j], acc[i][j], 0, 0, 0);
    }

    // epilogue: C/D layout col=lane&15, row=(lane>>4)*4+reg  [m89-verified]
    const int rbase = m0 + wrow + (lane >> 4) * 4;
    const int cbase = n0 + wcol + l15;
#pragma unroll
    for (int i = 0; i < MR; i++) {
#pragma unroll
        for (int j = 0; j < 4; j++) {
            int col = cbase + j * 16;
            float bv = bias ? bias[col] : 0.f;
#pragma unroll
            for (int r = 0; r < 4; r++) {
                int row = rbase + i * 16 + r;
                float v = acc[i][j][r] + bv;
                float* dst = &C[(size_t)row * N + col];
                if (accumulate) v += *dst;
                *dst = v;
            }
        }
    }
}

// ---------------- fused conv+silu+xproj+dtproj (one block per row) ----------------
// reads xz (x half, row stride 1024); writes xc (f32), dbc[48], dlt (softplus)
__global__ __launch_bounds__(256) void mid_fused(const float* __restrict__ xz,
                                                 const float* __restrict__ cw,
                                                 const float* __restrict__ cb,
                                                 const float* __restrict__ xpw,
                                                 const float* __restrict__ dtw,
                                                 const float* __restrict__ dtb,
                                                 float* __restrict__ xc,
                                                 float* __restrict__ dbc,
                                                 float* __restrict__ dlt) {
    const int r = blockIdx.x;
    const int l = r & (Lq - 1);
    const int tid = threadIdx.x;
    __shared__ float xcs[EDq];
    __shared__ float dbs[16];

    // causal depthwise conv K=4 + silu (2 channels per thread)
#pragma unroll
    for (int p = 0; p < 2; p++) {
        int e = tid + p * 256;
        float acc = cb[e];
#pragma unroll
        for (int i = 0; i < 4; i++) {
            int dl = i - 3;
            if (l + dl >= 0) acc = fmaf(xz[(size_t)(r + dl) * 1024 + e], cw[e * 4 + i], acc);
        }
        float s = acc / (1.0f + __expf(-acc));
        xcs[e] = s;
        xc[(size_t)r * EDq + e] = s;
    }
    __syncthreads();

    // x_proj: 48 outputs, 4 lanes per output (each covers 128 of K=512)
    const int j = tid >> 2, sub = tid & 3;
    float part = 0.f;
    if (j < 48) {
        const float* wr = &xpw[j * EDq + sub * 128];
        const float* xr = &xcs[sub * 128];
        for (int k = 0; k < 128; k += 4) {
            float4 wv = *(const float4*)&wr[k];
            float4 xv = *(const float4*)&xr[k];
            part = fmaf(wv.x, xv.x, part);
            part = fmaf(wv.y, xv.y, part);
            part = fmaf(wv.z, xv.z, part);
            part = fmaf(wv.w, xv.w, part);
        }
    }
    part += __shfl_xor(part, 1);
    part += __shfl_xor(part, 2);
    if (j < 48 && sub == 0) {
        dbc[(size_t)r * 48 + j] = part;
        if (j < 16) dbs[j] = part;
    }
    __syncthreads();

    // dt_proj + softplus (2 channels per thread)
#pragma unroll
    for (int p = 0; p < 2; p++) {
        int e = tid + p * 256;
        const float* wr = &dtw[e * 16];
        float acc = dtb[e];
#pragma unroll
        for (int k = 0; k < 16; k++) acc = fmaf(dbs[k], wr[k], acc);
        float sp = (acc > 20.f) ? acc : log1pf(__expf(acc));
        dlt[(size_t)r * EDq + e] = sp;
    }
}

// ---------------- scan pass 1: per (b,e,chunk) local scan ----------------
__global__ __launch_bounds__(256) void scan_pass1(const float* __restrict__ dlt,
                                                  const float* __restrict__ xc,
                                                  const float* __restrict__ dbc,
                                                  const float* __restrict__ A_log,
                                                  float* __restrict__ cA,
                                                  float* __restrict__ cB) {
    int gid = blockIdx.x * 256 + threadIdx.x;   // < B*NC*ED = 65536
    int e = gid & (EDq - 1);
    int bc = gid >> 9;                           // b*NC + c
    int rbase = bc * LCq;

    float Aa[16];
#pragma unroll
    for (int n = 0; n < 16; n++) Aa[n] = -__expf(A_log[e * 16 + n]);
    float pA[16], hB[16];
#pragma unroll
    for (int n = 0; n < 16; n++) { pA[n] = 1.f; hB[n] = 0.f; }

    for (int t = 0; t < LCq; t++) {
        int r = rbase + t;
        float d = dlt[(size_t)r * EDq + e];
        float xv = xc[(size_t)r * EDq + e];
        float dx = d * xv;
        const float4* Bp = (const float4*)&dbc[(size_t)r * 48 + 16];
        float4 B0 = Bp[0], B1 = Bp[1], B2 = Bp[2], B3 = Bp[3];
        float Bm[16] = {B0.x, B0.y, B0.z, B0.w, B1.x, B1.y, B1.z, B1.w,
                        B2.x, B2.y, B2.z, B2.w, B3.x, B3.y, B3.z, B3.w};
#pragma unroll
        for (int n = 0; n < 16; n++) {
            float dA = __expf(d * Aa[n]);
            hB[n] = fmaf(dA, hB[n], dx * Bm[n]);
            pA[n] *= dA;
        }
    }
    size_t ob = (size_t)gid * 16;
#pragma unroll
    for (int n = 0; n < 16; n++) { cA[ob + n] = pA[n]; cB[ob + n] = hB[n]; }
}

// ---------------- scan chunk combine (sequential over NC chunks) ----------------
__global__ __launch_bounds__(256) void scan_combine(const float* __restrict__ cA,
                                                    const float* __restrict__ cB,
                                                    float* __restrict__ cP) {
    int idx = blockIdx.x * 256 + threadIdx.x;   // < B*ED*N = 16384
    int en = idx & 8191;                         // e*16+n
    int b = idx >> 13;
    float hc = 0.f;
    for (int c = 0; c < NCq; c++) {
        size_t base = ((size_t)(b * NCq + c) << 13) + en;
        cP[base] = hc;
        hc = fmaf(cA[base], hc, cB[base]);
    }
}

// ---------------- scan pass 2: recompute with prefix, fuse y = (hs.C + D*xc)*silu(z) ----
// writes y as bf16 (feeds out_proj MFMA GEMM)
__global__ __launch_bounds__(256) void scan_pass2(const float* __restrict__ dlt,
                                                  const float* __restrict__ xc,
                                                  const float* __restrict__ dbc,
                                                  const float* __restrict__ A_log,
                                                  const float* __restrict__ cP,
                                                  const float* __restrict__ Dp,
                                                  const float* __restrict__ xz,
                                                  unsigned short* __restrict__ y) {
    int gid = blockIdx.x * 256 + threadIdx.x;
    int e = gid & (EDq - 1);
    int bc = gid >> 9;
    int rbase = bc * LCq;

    float Aa[16];
#pragma unroll
    for (int n = 0; n < 16; n++) Aa[n] = -__expf(A_log[e * 16 + n]);
    float hh[16];
    size_t pb = (size_t)gid * 16;
#pragma unroll
    for (int n = 0; n < 16; n++) hh[n] = cP[pb + n];
    float Dv = Dp[e];

    for (int t = 0; t < LCq; t++) {
        int r = rbase + t;
        float d = dlt[(size_t)r * EDq + e];
        float xv = xc[(size_t)r * EDq + e];
        float dx = d * xv;
        const float4* Bp = (const float4*)&dbc[(size_t)r * 48 + 16];
        float4 B0 = Bp[0], B1 = Bp[1], B2 = Bp[2], B3 = Bp[3];
        float Bm[16] = {B0.x, B0.y, B0.z, B0.w, B1.x, B1.y, B1.z, B1.w,
                        B2.x, B2.y, B2.z, B2.w, B3.x, B3.y, B3.z, B3.w};
        const float4* Cp = (const float4*)&dbc[(size_t)r * 48 + 32];
        float4 C0 = Cp[0], C1 = Cp[1], C2 = Cp[2], C3 = Cp[3];
        float Cm[16] = {C0.x, C0.y, C0.z, C0.w, C1.x, C1.y, C1.z, C1.w,
                        C2.x, C2.y, C2.z, C2.w, C3.x, C3.y, C3.z, C3.w};
        float cacc = 0.f;
#pragma unroll
        for (int n = 0; n < 16; n++) {
            float dA = __expf(d * Aa[n]);
            hh[n] = fmaf(dA, hh[n], dx * Bm[n]);
            cacc = fmaf(hh[n], Cm[n], cacc);
        }
        float yv = fmaf(Dv, xv, cacc);
        float zv = xz[(size_t)r * 1024 + EDq + e];
        float sz = zv / (1.0f + __expf(-zv));
        y[(size_t)r * EDq + e] = to_bf16(yv * sz);
    }
}

// ---------------- launch ----------------
extern "C" void kernel_launch(void* const* d_in, const int* in_sizes, int n_in,
                              void* d_out, int out_size, void* d_ws, size_t ws_size,
                              hipStream_t stream) {
    const int*   x         = (const int*)d_in[0];
    const float* embed_t   = (const float*)d_in[1];
    const float* rms_w     = (const float*)d_in[2];
    const float* in_proj_w = (const float*)d_in[3];
    const float* conv_w    = (const float*)d_in[4];
    const float* conv_b    = (const float*)d_in[5];
    const float* x_proj_w  = (const float*)d_in[6];
    const float* dt_proj_w = (const float*)d_in[7];
    const float* dt_proj_b = (const float*)d_in[8];
    const float* A_log     = (const float*)d_in[9];
    const float* D_p       = (const float*)d_in[10];
    const float* out_proj_w= (const float*)d_in[11];
    const float* norm_w    = (const float*)d_in[12];
    const float* norm_b    = (const float*)d_in[13];
    const float* head_w    = (const float*)d_in[14];
    const float* head_b    = (const float*)d_in[15];
    float* out = (float*)d_out;

    float* ws = (float*)d_ws;
    float* h    = ws;                           // R*D
    float* xz   = h    + (size_t)Rq * Dq;       // R*1024
    float* xc   = xz   + (size_t)Rq * 1024;     // R*ED
    float* dbc  = xc   + (size_t)Rq * EDq;      // R*48
    float* dlt  = dbc  + (size_t)Rq * 48;       // R*ED
    float* cA   = dlt  + (size_t)Rq * EDq;      // B*NC*ED*N = 1,048,576
    float* cB   = cA   + (size_t)Bq * NCq * EDq * Nst;
    float* cP   = cB   + (size_t)Bq * NCq * EDq * Nst;
    float* fend = cP   + (size_t)Bq * NCq * EDq * Nst;

    unsigned short* xin16 = (unsigned short*)fend;          // R*D bf16
    unsigned short* yb16  = xin16 + (size_t)Rq * Dq;        // R*ED bf16
    unsigned short* hn16  = yb16  + (size_t)Rq * EDq;       // R*D bf16
    unsigned short* w16i  = hn16  + (size_t)Rq * Dq;        // 4*1024*256
    unsigned short* w16o  = w16i  + (size_t)NLq * 1024 * Dq;  // 4*256*512
    unsigned short* w16h  = w16o  + (size_t)NLq * Dq * EDq;   // 32000*256

    // weight conversions (per-call, deterministic; ~50 MB traffic)
    convert_bf16<<<(NLq * 1024 * Dq) / 1024, 256, 0, stream>>>(in_proj_w, w16i, NLq * 1024 * Dq);
    convert_bf16<<<(NLq * Dq * EDq) / 1024, 256, 0, stream>>>(out_proj_w, w16o, NLq * Dq * EDq);
    convert_bf16<<<(Vq * Dq) / 1024, 256, 0, stream>>>(head_w, w16h, Vq * Dq);

    embed_kernel<<<Rq, 256, 0, stream>>>(x, embed_t, h);

    for (int i = 0; i < NLq; i++) {
        rmsnorm_kernel<<<Rq, 256, 0, stream>>>(h, rms_w + i * Dq, xin16);
        gemm_mfma<128><<<dim3(1024 / 128, Rq / 128), 256, 0, stream>>>(
            xin16, w16i + (size_t)i * 1024 * Dq, nullptr, xz, Rq, 1024, Dq, 0);
        mid_fused<<<Rq, 256, 0, stream>>>(
            xz, conv_w + i * EDq * Kq, conv_b + i * EDq,
            x_proj_w + (size_t)i * 48 * EDq,
            dt_proj_w + (size_t)i * EDq * DTq, dt_proj_b + i * EDq,
            xc, dbc, dlt);
        scan_pass1<<<(Bq * NCq * EDq) / 256, 256, 0, stream>>>(
            dlt, xc, dbc, A_log + i * EDq * Nst, cA, cB);
        scan_combine<<<64, 256, 0, stream>>>(cA, cB, cP);
        scan_pass2<<<(Bq * NCq * EDq) / 256, 256, 0, stream>>>(
            dlt, xc, dbc, A_log + i * EDq * Nst, cP, D_p + i * EDq, xz, yb16);
        gemm_mfma<64><<<dim3(Dq / 64, Rq / 128), 256, 0, stream>>>(
            yb16, w16o + (size_t)i * Dq * EDq, nullptr, h, Rq, Dq, EDq, 1);
    }

    layernorm_kernel<<<Rq, 256, 0, stream>>>(h, norm_w, norm_b, hn16);
    gemm_mfma<128><<<dim3(Vq / 128, Rq / 128), 256, 0, stream>>>(
        hn16, w16h, head_b, out, Rq, Vq, Dq, 0);
}

// Round 4
// 787.323 us; speedup vs baseline: 2.8103x; 1.0339x over previous
//
#include <hip/hip_runtime.h>
#include <hip/hip_bf16.h>
#include <math.h>

// Problem constants
#define Bq   2
#define Lq   2048
#define Dq   256
#define NLq  4
#define Nst  16
#define EDq  512
#define Kq   4
#define DTq  16
#define Vq   32000
#define Rq   (Bq*Lq)          // 4096 rows
#define NCq  256              // scan chunks
#define LCq  (Lq/NCq)         // 8 per chunk

typedef __attribute__((ext_vector_type(8))) __bf16 bf16x8v;
typedef __attribute__((ext_vector_type(4))) float f32x4v;
typedef __attribute__((address_space(1))) const void GV;
typedef __attribute__((address_space(3))) void LV;

__device__ __forceinline__ unsigned short to_bf16(float f) {
    unsigned int u = __float_as_uint(f);
    unsigned int r = (u + 0x7FFFu + ((u >> 16) & 1u)) >> 16;
    return (unsigned short)r;
}

// ---------------- f32 -> bf16 weight conversion (4 elems/thread) ----------------
__global__ __launch_bounds__(256) void convert_bf16(const float* __restrict__ in,
                                                    unsigned short* __restrict__ out, int n) {
    int i = (blockIdx.x * 256 + threadIdx.x) * 4;
    if (i + 3 < n) {
        float4 v = *(const float4*)&in[i];
        ushort4 o;
        o.x = to_bf16(v.x); o.y = to_bf16(v.y); o.z = to_bf16(v.z); o.w = to_bf16(v.w);
        *(ushort4*)&out[i] = o;
    }
}

// ---------------- embed ----------------
__global__ __launch_bounds__(256) void embed_kernel(const int* __restrict__ x,
                                                    const float* __restrict__ et,
                                                    float* __restrict__ h) {
    int r = blockIdx.x;
    int d = threadIdx.x;
    h[r * Dq + d] = et[x[r] * Dq + d];
}

// ---------------- rmsnorm (block per row, D=256), bf16 out ----------------
__global__ __launch_bounds__(256) void rmsnorm_kernel(const float* __restrict__ h,
                                                      const float* __restrict__ w,
                                                      unsigned short* __restrict__ out) {
    int r = blockIdx.x;
    int d = threadIdx.x;
    float v = h[r * Dq + d];
    float ss = v * v;
#pragma unroll
    for (int o = 32; o > 0; o >>= 1) ss += __shfl_down(ss, o);
    __shared__ float sb[4];
    if ((threadIdx.x & 63) == 0) sb[threadIdx.x >> 6] = ss;
    __syncthreads();
    float tot = sb[0] + sb[1] + sb[2] + sb[3];
    float scale = rsqrtf(tot * (1.0f / Dq) + 1e-5f);
    out[r * Dq + d] = to_bf16(v * scale * w[d]);
}

// ---------------- layernorm (block per row, D=256), bf16 out ----------------
__global__ __launch_bounds__(256) void layernorm_kernel(const float* __restrict__ h,
                                                        const float* __restrict__ w,
                                                        const float* __restrict__ b,
                                                        unsigned short* __restrict__ out) {
    int r = blockIdx.x;
    int d = threadIdx.x;
    float v = h[r * Dq + d];
    float s = v, s2 = v * v;
#pragma unroll
    for (int o = 32; o > 0; o >>= 1) { s += __shfl_down(s, o); s2 += __shfl_down(s2, o); }
    __shared__ float sb[8];
    if ((threadIdx.x & 63) == 0) { sb[threadIdx.x >> 6] = s; sb[4 + (threadIdx.x >> 6)] = s2; }
    __syncthreads();
    float S  = sb[0] + sb[1] + sb[2] + sb[3];
    float S2 = sb[4] + sb[5] + sb[6] + sb[7];
    float mu = S * (1.0f / Dq);
    float var = S2 * (1.0f / Dq) - mu * mu;
    out[r * Dq + d] = to_bf16((v - mu) * rsqrtf(var + 1e-5f) * w[d] + b[d]);
}

// ---------------- bf16 MFMA GEMM: C[m,n] (+=) sum_k A[m,k]*W[n,k] (+bias[n]) ----
// m97 structure, parameterized tile BMxBN, BK=32, 4 waves, global_load_lds w=16,
// linear LDS, bijective XCD swizzle. M div BM, N div BN, K div 32.
template<int BM, int BN>
__global__ __launch_bounds__(256) void gemm_mfma(const unsigned short* __restrict__ A,
                                                 const unsigned short* __restrict__ W,
                                                 const float* __restrict__ bias,
                                                 float* __restrict__ C,
                                                 int M, int N, int K, int accumulate) {
    constexpr int WGM = (BM == 128 && BN == 128) ? 2 : (BM == 128 ? 4 : 2);
    constexpr int WGN = 4 / WGM;
    constexpr int MR = BM / (WGM * 16);
    constexpr int NR = BN / (WGN * 16);
    constexpr int AR = BM / 64;   // A staging rounds (16 rows/wave/round)
    constexpr int BR = BN / 64;
    __shared__ unsigned short As[BM * 32];
    __shared__ unsigned short Bs[BN * 32];

    // XCD-aware bijective swizzle of the flattened block id
    const int gx = gridDim.x;
    const int nwg = gx * gridDim.y;
    int flat = blockIdx.y * gx + blockIdx.x;
    if ((nwg & 7) == 0) {
        int cpx = nwg >> 3;
        flat = (flat & 7) * cpx + (flat >> 3);
    }
    const int m0 = (flat / gx) * BM, n0 = (flat % gx) * BN;

    const int tid = threadIdx.x;
    const int wid = tid >> 6, lane = tid & 63;
    const int wrow = (wid / WGN) * (BM / WGM);
    const int wcol = (wid % WGN) * (BN / WGN);

    f32x4v acc[MR][NR];
#pragma unroll
    for (int i = 0; i < MR; i++)
#pragma unroll
        for (int j = 0; j < NR; j++) acc[i][j] = (f32x4v){0.f, 0.f, 0.f, 0.f};

    const int srow = lane >> 2;          // 0..15
    const int skoff = (lane & 3) * 8;    // 0,8,16,24
    const unsigned short* gA = A + (size_t)(m0 + wid * (16 * AR) + srow) * K + skoff;
    unsigned short* lA = As + wid * (512 * AR) + lane * 8;
    const unsigned short* gW = W + (size_t)(n0 + wid * (16 * BR) + srow) * K + skoff;
    unsigned short* lB = Bs + wid * (512 * BR) + lane * 8;

    const int l15 = lane & 15, lk = (lane >> 4) * 8;

    for (int kt = 0; kt < K; kt += 32) {
        __syncthreads();  // previous iteration's ds_reads complete
#pragma unroll
        for (int p = 0; p < AR; p++)
            __builtin_amdgcn_global_load_lds((GV*)(gA + kt + (size_t)p * 16 * K),
                                             (LV*)(lA + p * 512), 16, 0, 0);
#pragma unroll
        for (int p = 0; p < BR; p++)
            __builtin_amdgcn_global_load_lds((GV*)(gW + kt + (size_t)p * 16 * K),
                                             (LV*)(lB + p * 512), 16, 0, 0);
        __syncthreads();  // drains vmcnt(0): staged data visible

        bf16x8v a[MR], b[NR];
#pragma unroll
        for (int i = 0; i < MR; i++)
            a[i] = *(const bf16x8v*)&As[(wrow + i * 16 + l15) * 32 + lk];
#pragma unroll
        for (int j = 0; j < NR; j++)
            b[j] = *(const bf16x8v*)&Bs[(wcol + j * 16 + l15) * 32 + lk];
#pragma unroll
        for (int i = 0; i < MR; i++)
#pragma unroll
            for (int j = 0; j < NR; j++)
                acc[i][j] = __builtin_amdgcn_mfma_f32_16x16x32_bf16(a[i], b[j], acc[i][j], 0, 0, 0);
    }

    // epilogue: C/D layout col=lane&15, row=(lane>>4)*4+reg  [m89-verified]
    const int rbase = m0 + wrow + (lane >> 4) * 4;
    const int cbase = n0 + wcol + l15;
#pragma unroll
    for (int i = 0; i < MR; i++) {
#pragma unroll
        for (int j = 0; j < NR; j++) {
            int col = cbase + j * 16;
            float bv = bias ? bias[col] : 0.f;
#pragma unroll
            for (int r = 0; r < 4; r++) {
                int row = rbase + i * 16 + r;
                float v = acc[i][j][r] + bv;
                float* dst = &C[(size_t)row * N + col];
                if (accumulate) v += *dst;
                *dst = v;
            }
        }
    }
}

// ---------------- fused conv+silu+xproj+dtproj (one block per row) ----------------
__global__ __launch_bounds__(256) void mid_fused(const float* __restrict__ xz,
                                                 const float* __restrict__ cw,
                                                 const float* __restrict__ cb,
                                                 const float* __restrict__ xpw,
                                                 const float* __restrict__ dtw,
                                                 const float* __restrict__ dtb,
                                                 float* __restrict__ xc,
                                                 float* __restrict__ dbc,
                                                 float* __restrict__ dlt) {
    const int r = blockIdx.x;
    const int l = r & (Lq - 1);
    const int tid = threadIdx.x;
    __shared__ float xcs[EDq];
    __shared__ float dbs[16];

    // causal depthwise conv K=4 + silu (2 channels per thread)
#pragma unroll
    for (int p = 0; p < 2; p++) {
        int e = tid + p * 256;
        float acc = cb[e];
#pragma unroll
        for (int i = 0; i < 4; i++) {
            int dl = i - 3;
            if (l + dl >= 0) acc = fmaf(xz[(size_t)(r + dl) * 1024 + e], cw[e * 4 + i], acc);
        }
        float s = acc / (1.0f + __expf(-acc));
        xcs[e] = s;
        xc[(size_t)r * EDq + e] = s;
    }
    __syncthreads();

    // x_proj: 48 outputs, 4 lanes per output (each covers 128 of K=512)
    const int j = tid >> 2, sub = tid & 3;
    float part = 0.f;
    if (j < 48) {
        const float* wr = &xpw[j * EDq + sub * 128];
        const float* xr = &xcs[sub * 128];
        for (int k = 0; k < 128; k += 4) {
            float4 wv = *(const float4*)&wr[k];
            float4 xv = *(const float4*)&xr[k];
            part = fmaf(wv.x, xv.x, part);
            part = fmaf(wv.y, xv.y, part);
            part = fmaf(wv.z, xv.z, part);
            part = fmaf(wv.w, xv.w, part);
        }
    }
    part += __shfl_xor(part, 1);
    part += __shfl_xor(part, 2);
    if (j < 48 && sub == 0) {
        dbc[(size_t)r * 48 + j] = part;
        if (j < 16) dbs[j] = part;
    }
    __syncthreads();

    // dt_proj + softplus (2 channels per thread)
#pragma unroll
    for (int p = 0; p < 2; p++) {
        int e = tid + p * 256;
        const float* wr = &dtw[e * 16];
        float acc = dtb[e];
#pragma unroll
        for (int k = 0; k < 16; k++) acc = fmaf(dbs[k], wr[k], acc);
        float sp = (acc > 20.f) ? acc : log1pf(__expf(acc));
        dlt[(size_t)r * EDq + e] = sp;
    }
}

// ---------------- scan pass 1: per (b,e,chunk) local scan ----------------
__global__ __launch_bounds__(256) void scan_pass1(const float* __restrict__ dlt,
                                                  const float* __restrict__ xc,
                                                  const float* __restrict__ dbc,
                                                  const float* __restrict__ A_log,
                                                  float* __restrict__ cA,
                                                  float* __restrict__ cB) {
    int gid = blockIdx.x * 256 + threadIdx.x;   // < B*NC*ED
    int e = gid & (EDq - 1);
    int bc = gid >> 9;                           // b*NC + c
    int rbase = bc * LCq;

    float Aa[16];
#pragma unroll
    for (int n = 0; n < 16; n++) Aa[n] = -__expf(A_log[e * 16 + n]);
    float pA[16], hB[16];
#pragma unroll
    for (int n = 0; n < 16; n++) { pA[n] = 1.f; hB[n] = 0.f; }

    for (int t = 0; t < LCq; t++) {
        int r = rbase + t;
        float d = dlt[(size_t)r * EDq + e];
        float xv = xc[(size_t)r * EDq + e];
        float dx = d * xv;
        const float4* Bp = (const float4*)&dbc[(size_t)r * 48 + 16];
        float4 B0 = Bp[0], B1 = Bp[1], B2 = Bp[2], B3 = Bp[3];
        float Bm[16] = {B0.x, B0.y, B0.z, B0.w, B1.x, B1.y, B1.z, B1.w,
                        B2.x, B2.y, B2.z, B2.w, B3.x, B3.y, B3.z, B3.w};
#pragma unroll
        for (int n = 0; n < 16; n++) {
            float dA = __expf(d * Aa[n]);
            hB[n] = fmaf(dA, hB[n], dx * Bm[n]);
            pA[n] *= dA;
        }
    }
    size_t ob = (size_t)gid * 16;
#pragma unroll
    for (int n = 0; n < 16; n++) { cA[ob + n] = pA[n]; cB[ob + n] = hB[n]; }
}

// ---------------- scan chunk combine (sequential over NC chunks) ----------------
__global__ __launch_bounds__(256) void scan_combine(const float* __restrict__ cA,
                                                    const float* __restrict__ cB,
                                                    float* __restrict__ cP) {
    int idx = blockIdx.x * 256 + threadIdx.x;   // < B*ED*N = 16384
    int en = idx & 8191;                         // e*16+n
    int b = idx >> 13;
    float hc = 0.f;
    for (int c = 0; c < NCq; c++) {
        size_t base = ((size_t)(b * NCq + c) << 13) + en;
        cP[base] = hc;
        hc = fmaf(cA[base], hc, cB[base]);
    }
}

// ---------------- scan pass 2: recompute with prefix, fuse y = (hs.C + D*xc)*silu(z) ----
// writes y as bf16 (feeds out_proj MFMA GEMM)
__global__ __launch_bounds__(256) void scan_pass2(const float* __restrict__ dlt,
                                                  const float* __restrict__ xc,
                                                  const float* __restrict__ dbc,
                                                  const float* __restrict__ A_log,
                                                  const float* __restrict__ cP,
                                                  const float* __restrict__ Dp,
                                                  const float* __restrict__ xz,
                                                  unsigned short* __restrict__ y) {
    int gid = blockIdx.x * 256 + threadIdx.x;
    int e = gid & (EDq - 1);
    int bc = gid >> 9;
    int rbase = bc * LCq;

    float Aa[16];
#pragma unroll
    for (int n = 0; n < 16; n++) Aa[n] = -__expf(A_log[e * 16 + n]);
    float hh[16];
    size_t pb = (size_t)gid * 16;
#pragma unroll
    for (int n = 0; n < 16; n++) hh[n] = cP[pb + n];
    float Dv = Dp[e];

    for (int t = 0; t < LCq; t++) {
        int r = rbase + t;
        float d = dlt[(size_t)r * EDq + e];
        float xv = xc[(size_t)r * EDq + e];
        float dx = d * xv;
        const float4* Bp = (const float4*)&dbc[(size_t)r * 48 + 16];
        float4 B0 = Bp[0], B1 = Bp[1], B2 = Bp[2], B3 = Bp[3];
        float Bm[16] = {B0.x, B0.y, B0.z, B0.w, B1.x, B1.y, B1.z, B1.w,
                        B2.x, B2.y, B2.z, B2.w, B3.x, B3.y, B3.z, B3.w};
        const float4* Cp = (const float4*)&dbc[(size_t)r * 48 + 32];
        float4 C0 = Cp[0], C1 = Cp[1], C2 = Cp[2], C3 = Cp[3];
        float Cm[16] = {C0.x, C0.y, C0.z, C0.w, C1.x, C1.y, C1.z, C1.w,
                        C2.x, C2.y, C2.z, C2.w, C3.x, C3.y, C3.z, C3.w};
        float cacc = 0.f;
#pragma unroll
        for (int n = 0; n < 16; n++) {
            float dA = __expf(d * Aa[n]);
            hh[n] = fmaf(dA, hh[n], dx * Bm[n]);
            cacc = fmaf(hh[n], Cm[n], cacc);
        }
        float yv = fmaf(Dv, xv, cacc);
        float zv = xz[(size_t)r * 1024 + EDq + e];
        float sz = zv / (1.0f + __expf(-zv));
        y[(size_t)r * EDq + e] = to_bf16(yv * sz);
    }
}

// ---------------- launch ----------------
extern "C" void kernel_launch(void* const* d_in, const int* in_sizes, int n_in,
                              void* d_out, int out_size, void* d_ws, size_t ws_size,
                              hipStream_t stream) {
    const int*   x         = (const int*)d_in[0];
    const float* embed_t   = (const float*)d_in[1];
    const float* rms_w     = (const float*)d_in[2];
    const float* in_proj_w = (const float*)d_in[3];
    const float* conv_w    = (const float*)d_in[4];
    const float* conv_b    = (const float*)d_in[5];
    const float* x_proj_w  = (const float*)d_in[6];
    const float* dt_proj_w = (const float*)d_in[7];
    const float* dt_proj_b = (const float*)d_in[8];
    const float* A_log     = (const float*)d_in[9];
    const float* D_p       = (const float*)d_in[10];
    const float* out_proj_w= (const float*)d_in[11];
    const float* norm_w    = (const float*)d_in[12];
    const float* norm_b    = (const float*)d_in[13];
    const float* head_w    = (const float*)d_in[14];
    const float* head_b    = (const float*)d_in[15];
    float* out = (float*)d_out;

    float* ws = (float*)d_ws;
    float* h    = ws;                           // R*D
    float* xz   = h    + (size_t)Rq * Dq;       // R*1024
    float* xc   = xz   + (size_t)Rq * 1024;     // R*ED
    float* dbc  = xc   + (size_t)Rq * EDq;      // R*48
    float* dlt  = dbc  + (size_t)Rq * 48;       // R*ED
    float* cA   = dlt  + (size_t)Rq * EDq;      // B*NC*ED*N
    float* cB   = cA   + (size_t)Bq * NCq * EDq * Nst;
    float* cP   = cB   + (size_t)Bq * NCq * EDq * Nst;
    float* fend = cP   + (size_t)Bq * NCq * EDq * Nst;

    unsigned short* xin16 = (unsigned short*)fend;          // R*D bf16
    unsigned short* yb16  = xin16 + (size_t)Rq * Dq;        // R*ED bf16
    unsigned short* hn16  = yb16  + (size_t)Rq * EDq;       // R*D bf16
    unsigned short* w16i  = hn16  + (size_t)Rq * Dq;        // 4*1024*256
    unsigned short* w16o  = w16i  + (size_t)NLq * 1024 * Dq;  // 4*256*512
    unsigned short* w16h  = w16o  + (size_t)NLq * Dq * EDq;   // 32000*256

    // weight conversions (per-call, deterministic; ~50 MB traffic)
    convert_bf16<<<(NLq * 1024 * Dq) / 1024, 256, 0, stream>>>(in_proj_w, w16i, NLq * 1024 * Dq);
    convert_bf16<<<(NLq * Dq * EDq) / 1024, 256, 0, stream>>>(out_proj_w, w16o, NLq * Dq * EDq);
    convert_bf16<<<(Vq * Dq) / 1024, 256, 0, stream>>>(head_w, w16h, Vq * Dq);

    embed_kernel<<<Rq, 256, 0, stream>>>(x, embed_t, h);

    for (int i = 0; i < NLq; i++) {
        rmsnorm_kernel<<<Rq, 256, 0, stream>>>(h, rms_w + i * Dq, xin16);
        gemm_mfma<128, 64><<<dim3(1024 / 64, Rq / 128), 256, 0, stream>>>(
            xin16, w16i + (size_t)i * 1024 * Dq, nullptr, xz, Rq, 1024, Dq, 0);
        mid_fused<<<Rq, 256, 0, stream>>>(
            xz, conv_w + i * EDq * Kq, conv_b + i * EDq,
            x_proj_w + (size_t)i * 48 * EDq,
            dt_proj_w + (size_t)i * EDq * DTq, dt_proj_b + i * EDq,
            xc, dbc, dlt);
        scan_pass1<<<(Bq * NCq * EDq) / 256, 256, 0, stream>>>(
            dlt, xc, dbc, A_log + i * EDq * Nst, cA, cB);
        scan_combine<<<64, 256, 0, stream>>>(cA, cB, cP);
        scan_pass2<<<(Bq * NCq * EDq) / 256, 256, 0, stream>>>(
            dlt, xc, dbc, A_log + i * EDq * Nst, cP, D_p + i * EDq, xz, yb16);
        gemm_mfma<64, 64><<<dim3(Dq / 64, Rq / 64), 256, 0, stream>>>(
            yb16, w16o + (size_t)i * Dq * EDq, nullptr, h, Rq, Dq, EDq, 1);
    }

    layernorm_kernel<<<Rq, 256, 0, stream>>>(h, norm_w, norm_b, hn16);
    gemm_mfma<128, 128><<<dim3(Vq / 128, Rq / 128), 256, 0, stream>>>(
        hn16, w16h, head_b, out, Rq, Vq, Dq, 0);
}